// Round 6
// baseline (485.958 us; speedup 1.0000x reference)
//
#include <hip/hip_runtime.h>

#define HF 128  // feature width (F == H == 128)
#define NXCD 8

__device__ __forceinline__ unsigned short f2bf(float f) {
    unsigned u = __float_as_uint(f);
    unsigned rounding = 0x7FFF + ((u >> 16) & 1);  // round-to-nearest-even
    return (unsigned short)((u + rounding) >> 16);
}

// ---------- phase A: bucket edges by col-range, packed 4B entries ----------
// entry = (c - g*step) << 17 | r   (needs step<=32768, N<=131072; here 6250/50000)
// Block-local two-phase append: LDS histogram -> one global cursor reserve per
// bucket -> regional writes. Avoids hot-frontier cross-XCD ping-pong.
__global__ __launch_bounds__(256) void bucket_edges(const int* __restrict__ row,
                                                    const int* __restrict__ col,
                                                    unsigned* __restrict__ buckets,
                                                    int* __restrict__ cursor,
                                                    int E, int step, unsigned magic,
                                                    int cap) {
    __shared__ int lhist[NXCD], lbase[NXCD], lofs[NXCD];
    int t = threadIdx.x;
    if (t < NXCD) { lhist[t] = 0; lofs[t] = 0; }
    __syncthreads();
    int e0 = blockIdx.x * 2048 + t * 8;
    int cc[8], rr[8], pg[8];
    unsigned pk[8];
    if (e0 + 8 <= E) {
        int4 c0 = *reinterpret_cast<const int4*>(col + e0);
        int4 c1 = *reinterpret_cast<const int4*>(col + e0 + 4);
        int4 r0 = *reinterpret_cast<const int4*>(row + e0);
        int4 r1 = *reinterpret_cast<const int4*>(row + e0 + 4);
        cc[0]=c0.x; cc[1]=c0.y; cc[2]=c0.z; cc[3]=c0.w;
        cc[4]=c1.x; cc[5]=c1.y; cc[6]=c1.z; cc[7]=c1.w;
        rr[0]=r0.x; rr[1]=r0.y; rr[2]=r0.z; rr[3]=r0.w;
        rr[4]=r1.x; rr[5]=r1.y; rr[6]=r1.z; rr[7]=r1.w;
    } else {
        #pragma unroll
        for (int i = 0; i < 8; ++i) {
            int e = e0 + i;
            cc[i] = (e < E) ? col[e] : -1;
            rr[i] = (e < E) ? row[e] : 0;
        }
    }
    #pragma unroll
    for (int i = 0; i < 8; ++i) {
        if (cc[i] >= 0) {
            int g = (int)(((unsigned long long)(unsigned)cc[i] * magic) >> 32);
            pg[i] = g;
            pk[i] = ((unsigned)(cc[i] - g * step) << 17) | (unsigned)rr[i];
            atomicAdd(&lhist[g], 1);
        } else {
            pg[i] = -1;
        }
    }
    __syncthreads();
    if (t < NXCD) lbase[t] = lhist[t] ? atomicAdd(&cursor[t], lhist[t]) : 0;
    __syncthreads();
    #pragma unroll
    for (int i = 0; i < 8; ++i) {
        if (pg[i] >= 0) {
            int pos = lbase[pg[i]] + atomicAdd(&lofs[pg[i]], 1);
            buckets[(size_t)pg[i] * cap + pos] = pk[i];
        }
    }
}

// ---------- phase B: per-XCD degree count from local bucket ----------
// group g streams only its own ~0.8MB bucket; cnt slice (25KB) stays L2-hot.
__global__ __launch_bounds__(256) void count_bucket(const unsigned* __restrict__ buckets,
                                                    const int* __restrict__ cursor,
                                                    int* __restrict__ cnt,
                                                    int step, int cap) {
    int g = blockIdx.x & (NXCD - 1);
    int sub = blockIdx.x >> 3;
    int nsub = gridDim.x >> 3;
    int sz = cursor[g];
    const unsigned* bk = buckets + (size_t)g * cap;
    int clo = g * step;
    for (int i = sub * 256 + threadIdx.x; i < sz; i += nsub * 256) {
        atomicAdd(&cnt[clo + (int)(bk[i] >> 17)], 1);
    }
}

// ---------- scan pass1 + dinv fused ----------
__global__ __launch_bounds__(256) void scan_pass1(const int* __restrict__ cnt,
                                                  int* __restrict__ rowptr,
                                                  int* __restrict__ blocksum,
                                                  float* __restrict__ dinv, int N) {
    __shared__ int s[256];
    int t = threadIdx.x;
    int i = blockIdx.x * 256 + t;
    int v = (i < N) ? cnt[i] : 0;
    if (i < N) dinv[i] = rsqrtf((float)v + 1.0f);
    s[t] = v;
    __syncthreads();
    for (int o = 1; o < 256; o <<= 1) {
        int tv = (t >= o) ? s[t - o] : 0;
        __syncthreads();
        s[t] += tv;
        __syncthreads();
    }
    if (i < N) rowptr[i] = s[t] - v;  // block-local exclusive
    if (t == 255) blocksum[blockIdx.x] = s[255];
}

// fused pass2+3: each block reduces blocksum[0..blockIdx) itself (nb <= 256),
// adds the base, and seeds fill[] with the final rowptr.
__global__ __launch_bounds__(256) void scan_pass23(int* __restrict__ rowptr,
                                                   const int* __restrict__ blocksum,
                                                   int* __restrict__ fill,
                                                   int N, int E, int nb) {
    __shared__ int s[256];
    int t = threadIdx.x;
    s[t] = (t < nb && t < blockIdx.x) ? blocksum[t] : 0;
    __syncthreads();
    for (int o = 128; o > 0; o >>= 1) {
        if (t < o) s[t] += s[t + o];
        __syncthreads();
    }
    int base = s[0];
    int i = blockIdx.x * 256 + t;
    if (i < N) {
        int v = rowptr[i] + base;
        rowptr[i] = v;
        fill[i] = v;
    }
    if (blockIdx.x == 0 && t == 0) rowptr[N] = E;
}

// ---------- phase D: per-XCD CSR fill from local bucket ----------
// bucket (0.8MB) + srow slice (0.8MB) + fill slice (25KB) all fit one L2:
// dirty lines accumulate fully -> writeback ~= payload.
__global__ __launch_bounds__(256) void fill_bucket(const unsigned* __restrict__ buckets,
                                                   const int* __restrict__ cursor,
                                                   int* __restrict__ fill,
                                                   int* __restrict__ srow,
                                                   int step, int cap) {
    int g = blockIdx.x & (NXCD - 1);
    int sub = blockIdx.x >> 3;
    int nsub = gridDim.x >> 3;
    int sz = cursor[g];
    const unsigned* bk = buckets + (size_t)g * cap;
    int clo = g * step;
    for (int i = sub * 256 + threadIdx.x; i < sz; i += nsub * 256) {
        unsigned p = bk[i];
        int c = clo + (int)(p >> 17);
        int pos = atomicAdd(&fill[c], 1);
        srow[pos] = (int)(p & 0x1FFFFu);
    }
}

// ---------- GEMM: Y[N,128](bf16) = rowscale[r] * (BNReLU?(X[N,128]) @ W[128,128]) ----------
__global__ __launch_bounds__(128) void gemm128(const float* __restrict__ X,
                                               const float* __restrict__ W,
                                               unsigned short* __restrict__ Y,
                                               const float* __restrict__ scale,
                                               const float* __restrict__ shift,
                                               const float* __restrict__ rowscale,
                                               int N, int applyBN) {
    __shared__ float xs[16][HF];
    int t = threadIdx.x;
    int row0 = blockIdx.x * 16;
    float sc = applyBN ? scale[t] : 1.0f;
    float sh = applyBN ? shift[t] : 0.0f;
    for (int r = 0; r < 16; ++r) {
        int rr = row0 + r;
        float v = (rr < N) ? X[(size_t)rr * HF + t] : 0.0f;
        if (applyBN) v = fmaxf(v * sc + sh, 0.0f);
        xs[r][t] = v;
    }
    __syncthreads();
    for (int r0 = 0; r0 < 16; r0 += 4) {
        float a0 = 0.f, a1 = 0.f, a2 = 0.f, a3 = 0.f;
        #pragma unroll 8
        for (int f = 0; f < HF; ++f) {
            float w = W[f * HF + t];
            a0 += xs[r0 + 0][f] * w;
            a1 += xs[r0 + 1][f] * w;
            a2 += xs[r0 + 2][f] * w;
            a3 += xs[r0 + 3][f] * w;
        }
        int rr = row0 + r0;
        if (rr + 0 < N) Y[(size_t)(rr + 0) * HF + t] = f2bf(a0 * rowscale[rr + 0]);
        if (rr + 1 < N) Y[(size_t)(rr + 1) * HF + t] = f2bf(a1 * rowscale[rr + 1]);
        if (rr + 2 < N) Y[(size_t)(rr + 2) * HF + t] = f2bf(a2 * rowscale[rr + 2]);
        if (rr + 3 < N) Y[(size_t)(rr + 3) * HF + t] = f2bf(a3 * rowscale[rr + 3]);
    }
}

// ---------- gather-side conv on pre-scaled bf16 XWs ----------
__global__ __launch_bounds__(256) void gather_conv(const int* __restrict__ rowptr,
                                                   const int* __restrict__ srow,
                                                   const float* __restrict__ dinv,
                                                   const unsigned short* __restrict__ XW,
                                                   const float* __restrict__ b,
                                                   float* __restrict__ OUT, int N) {
    int c = blockIdx.x * 16 + (threadIdx.x >> 4);
    int j = threadIdx.x & 15;  // 8 features per lane
    if (c >= N) return;
    int e = rowptr[c], end = rowptr[c + 1];
    float acc[8] = {0.f, 0.f, 0.f, 0.f, 0.f, 0.f, 0.f, 0.f};
    const unsigned M = 0xffff0000u;
    for (; e + 1 < end; e += 2) {
        int r0 = srow[e], r1 = srow[e + 1];
        uint4 u0 = *reinterpret_cast<const uint4*>(XW + (size_t)r0 * HF + j * 8);
        uint4 u1 = *reinterpret_cast<const uint4*>(XW + (size_t)r1 * HF + j * 8);
        acc[0] += __uint_as_float(u0.x << 16) + __uint_as_float(u1.x << 16);
        acc[1] += __uint_as_float(u0.x & M)   + __uint_as_float(u1.x & M);
        acc[2] += __uint_as_float(u0.y << 16) + __uint_as_float(u1.y << 16);
        acc[3] += __uint_as_float(u0.y & M)   + __uint_as_float(u1.y & M);
        acc[4] += __uint_as_float(u0.z << 16) + __uint_as_float(u1.z << 16);
        acc[5] += __uint_as_float(u0.z & M)   + __uint_as_float(u1.z & M);
        acc[6] += __uint_as_float(u0.w << 16) + __uint_as_float(u1.w << 16);
        acc[7] += __uint_as_float(u0.w & M)   + __uint_as_float(u1.w & M);
    }
    if (e < end) {
        int r0 = srow[e];
        uint4 u0 = *reinterpret_cast<const uint4*>(XW + (size_t)r0 * HF + j * 8);
        acc[0] += __uint_as_float(u0.x << 16);
        acc[1] += __uint_as_float(u0.x & M);
        acc[2] += __uint_as_float(u0.y << 16);
        acc[3] += __uint_as_float(u0.y & M);
        acc[4] += __uint_as_float(u0.z << 16);
        acc[5] += __uint_as_float(u0.z & M);
        acc[6] += __uint_as_float(u0.w << 16);
        acc[7] += __uint_as_float(u0.w & M);
    }
    float dc = dinv[c];
    uint4 xv = *reinterpret_cast<const uint4*>(XW + (size_t)c * HF + j * 8);
    acc[0] += __uint_as_float(xv.x << 16);
    acc[1] += __uint_as_float(xv.x & M);
    acc[2] += __uint_as_float(xv.y << 16);
    acc[3] += __uint_as_float(xv.y & M);
    acc[4] += __uint_as_float(xv.z << 16);
    acc[5] += __uint_as_float(xv.z & M);
    acc[6] += __uint_as_float(xv.w << 16);
    acc[7] += __uint_as_float(xv.w & M);
    float4 b0 = *reinterpret_cast<const float4*>(b + j * 8);
    float4 b1 = *reinterpret_cast<const float4*>(b + j * 8 + 4);
    float4 o0, o1;
    o0.x = dc * acc[0] + b0.x;
    o0.y = dc * acc[1] + b0.y;
    o0.z = dc * acc[2] + b0.z;
    o0.w = dc * acc[3] + b0.w;
    o1.x = dc * acc[4] + b1.x;
    o1.y = dc * acc[5] + b1.y;
    o1.z = dc * acc[6] + b1.z;
    o1.w = dc * acc[7] + b1.w;
    float* op = OUT + (size_t)c * HF + j * 8;
    *reinterpret_cast<float4*>(op) = o0;
    *reinterpret_cast<float4*>(op + 4) = o1;
}

// ---------- BN stats ----------
__global__ __launch_bounds__(128) void bn_stats(const float* __restrict__ Y,
                                                float* __restrict__ ssum,
                                                float* __restrict__ ssq, int N) {
    int t = threadIdx.x;
    float s = 0.f, sq = 0.f;
    for (int n = blockIdx.x; n < N; n += gridDim.x) {
        float v = Y[(size_t)n * HF + t];
        s += v;
        sq += v * v;
    }
    atomicAdd(&ssum[t], s);
    atomicAdd(&ssq[t], sq);
}

__global__ __launch_bounds__(128) void bn_finalize(const float* __restrict__ ssum,
                                                   const float* __restrict__ ssq,
                                                   const float* __restrict__ gamma,
                                                   const float* __restrict__ beta,
                                                   float* __restrict__ scale,
                                                   float* __restrict__ shift, int N) {
    int t = threadIdx.x;
    float invn = 1.0f / (float)N;
    float mu = ssum[t] * invn;
    float var = ssq[t] * invn - mu * mu;
    float sc = gamma[t] * rsqrtf(var + 1e-5f);
    scale[t] = sc;
    shift[t] = beta[t] - mu * sc;
}

// ---------- graph boundaries (batch sorted) ----------
__global__ void graph_bounds(const int* __restrict__ batch, int* __restrict__ gstart,
                             int N, int NG) {
    int g = blockIdx.x * blockDim.x + threadIdx.x;
    if (g > NG) return;
    int lo = 0, hi = N;
    while (lo < hi) {
        int mid = (lo + hi) >> 1;
        if (batch[mid] < g) lo = mid + 1; else hi = mid;
    }
    gstart[g] = lo;
}

// ---------- fused BN2+ReLU + mean/max/sum pool + classifier ----------
__global__ __launch_bounds__(256) void pool_classify(const float* __restrict__ B,
                                                     const int* __restrict__ gstart,
                                                     const float* __restrict__ scale,
                                                     const float* __restrict__ shift,
                                                     const float* __restrict__ Wc,
                                                     const float* __restrict__ bc,
                                                     float* __restrict__ out) {
    int g = blockIdx.x;
    int t = threadIdx.x & 127;
    int half = threadIdx.x >> 7;
    int s0 = gstart[g], s1 = gstart[g + 1];
    float sc = scale[t], sh = shift[t];
    float sum = 0.f, mx = 0.f;  // 0-init == empty-graph guard (post-ReLU v >= 0)
    for (int n = s0 + half; n < s1; n += 2) {
        float v = fmaxf(B[(size_t)n * HF + t] * sc + sh, 0.0f);
        sum += v;
        mx = fmaxf(mx, v);
    }
    __shared__ float shsum[2][HF], shmax[2][HF];
    __shared__ float red[3][HF];
    shsum[half][t] = sum;
    shmax[half][t] = mx;
    __syncthreads();
    if (half == 0) {
        sum += shsum[1][t];
        mx = fmaxf(mx, shmax[1][t]);
        float cntf = (float)(s1 - s0);
        float mean = sum / fmaxf(cntf, 1.0f);
        red[0][t] = mean * Wc[t * 3 + 0] + mx * Wc[(HF + t) * 3 + 0] + sum * Wc[(2 * HF + t) * 3 + 0];
        red[1][t] = mean * Wc[t * 3 + 1] + mx * Wc[(HF + t) * 3 + 1] + sum * Wc[(2 * HF + t) * 3 + 1];
        red[2][t] = mean * Wc[t * 3 + 2] + mx * Wc[(HF + t) * 3 + 2] + sum * Wc[(2 * HF + t) * 3 + 2];
    }
    __syncthreads();
    for (int o = 64; o > 0; o >>= 1) {
        if (half == 0 && t < o) {
            red[0][t] += red[0][t + o];
            red[1][t] += red[1][t + o];
            red[2][t] += red[2][t + o];
        }
        __syncthreads();
    }
    if (threadIdx.x < 3) out[g * 3 + threadIdx.x] = red[threadIdx.x][0] + bc[threadIdx.x];
}

extern "C" void kernel_launch(void* const* d_in, const int* in_sizes, int n_in,
                              void* d_out, int out_size, void* d_ws, size_t ws_size,
                              hipStream_t stream) {
    const float* x    = (const float*)d_in[0];
    const int*   ei   = (const int*)d_in[1];
    const int*   batch= (const int*)d_in[2];
    const float* W1   = (const float*)d_in[3];
    const float* b1   = (const float*)d_in[4];
    const float* g1   = (const float*)d_in[5];
    const float* be1  = (const float*)d_in[6];
    const float* W2   = (const float*)d_in[7];
    const float* b2   = (const float*)d_in[8];
    const float* g2   = (const float*)d_in[9];
    const float* be2  = (const float*)d_in[10];
    const float* Wc   = (const float*)d_in[11];
    const float* bc   = (const float*)d_in[12];
    float* out = (float*)d_out;

    const int N = in_sizes[0] / HF;
    const int E = in_sizes[1] / 2;
    const int NG = 256;
    const int* row = ei;
    const int* col = ei + E;
    const int total = N * HF;
    const int step = (N + NXCD - 1) / NXCD;
    const unsigned magic = (unsigned)(((1ULL << 32) + step - 1) / (unsigned)step);  // ceil(2^32/step)
    const int cap = (E * 3) / 8;  // 3x expected bucket size

    // workspace carve-up (256B aligned)
    char* w = (char*)d_ws;
    size_t off = 0;
    auto alloc = [&](size_t bytes) -> void* {
        void* p = w + off;
        off += (bytes + 255) & ~(size_t)255;
        return p;
    };
    int*            cnt_in   = (int*)alloc((size_t)N * 4);  // \ zeroed together
    int*            cursor   = (int*)alloc(NXCD * 4);       // /
    int*            fill     = (int*)alloc((size_t)N * 4);
    float*          dinv     = (float*)alloc((size_t)N * 4);
    int*            rowptr   = (int*)alloc(((size_t)N + 1) * 4);
    int*            blocksum = (int*)alloc(256 * 4);
    int*            gstart   = (int*)alloc((NG + 1) * 4);
    int*            srow     = (int*)alloc((size_t)E * 4);
    float*          ssum     = (float*)alloc(HF * 4);       // \ zeroed together
    float*          ssq      = (float*)alloc(HF * 4);       // /
    float*          scale    = (float*)alloc(HF * 4);
    float*          shift    = (float*)alloc(HF * 4);
    unsigned short* A        = (unsigned short*)alloc((size_t)total * 2);  // dinv-scaled xw (bf16)
    float*          B        = (float*)alloc((size_t)total * 4);           // conv out (f32)
    // buckets (8*cap*4 = 19.2MB) alias A+B (38.4MB): dead before gemm1 writes A
    unsigned*       buckets  = (unsigned*)A;

    const int T256 = 256;
    int gridGa   = (N + 15) / 16;
    int gridGemm = (N + 15) / 16;
    int nb       = (N + 255) / 256;   // scan blocks (requires N <= 65536)
    int gridBkt  = (E + 2047) / 2048;

    // --- CSR build (once; reused by both convs) ---
    hipMemsetAsync(cnt_in, 0, ((size_t)N * 4 + 255 & ~(size_t)255) + 256, stream);  // cnt_in + cursor
    bucket_edges<<<gridBkt, T256, 0, stream>>>(row, col, buckets, cursor, E, step, magic, cap);
    count_bucket<<<NXCD * 64, T256, 0, stream>>>(buckets, cursor, cnt_in, step, cap);
    scan_pass1<<<nb, 256, 0, stream>>>(cnt_in, rowptr, blocksum, dinv, N);
    scan_pass23<<<nb, 256, 0, stream>>>(rowptr, blocksum, fill, N, E, nb);
    fill_bucket<<<NXCD * 64, T256, 0, stream>>>(buckets, cursor, fill, srow, step, cap);
    graph_bounds<<<2, 129, 0, stream>>>(batch, gstart, N, NG);

    // --- conv1 (GEMM output rows pre-scaled by dinv) ---
    gemm128<<<gridGemm, 128, 0, stream>>>(x, W1, A, nullptr, nullptr, dinv, N, 0);
    gather_conv<<<gridGa, T256, 0, stream>>>(rowptr, srow, dinv, A, b1, B, N);
    hipMemsetAsync(ssum, 0, 2 * ((HF * 4 + 255) & ~255), stream);
    bn_stats<<<512, 128, 0, stream>>>(B, ssum, ssq, N);
    bn_finalize<<<1, 128, 0, stream>>>(ssum, ssq, g1, be1, scale, shift, N);

    // --- conv2 (BN1+ReLU fused into gemm input load) ---
    gemm128<<<gridGemm, 128, 0, stream>>>(B, W2, A, scale, shift, dinv, N, 1);
    gather_conv<<<gridGa, T256, 0, stream>>>(rowptr, srow, dinv, A, b2, B, N);
    hipMemsetAsync(ssum, 0, 2 * ((HF * 4 + 255) & ~255), stream);
    bn_stats<<<512, 128, 0, stream>>>(B, ssum, ssq, N);
    bn_finalize<<<1, 128, 0, stream>>>(ssum, ssq, g2, be2, scale, shift, N);

    // --- fused BN2+ReLU + pooling + classifier ---
    pool_classify<<<NG, 256, 0, stream>>>(B, gstart, scale, shift, Wc, bc, out);
}